// Round 2
// baseline (423.824 us; speedup 1.0000x reference)
//
#include <hip/hip_runtime.h>
#include <hip/hip_bf16.h>

// Problem: out[32768,128] = sigmoid(x[32768,1024] @ W[1024,128] + b[128]), all fp32.
// Strategy: bf16 MFMA (16x16x32), W pre-converted+swizzled to B-fragment order in d_ws.
// R2: latency-bound fix — register double-buffering across the k-loop + 2 waves/SIMD
//     (wave tile 16x128, block = 2 waves = 32 rows, grid = 1024 -> 4 blocks/CU).

typedef __bf16 bf16x8 __attribute__((ext_vector_type(8)));
typedef float  f32x4  __attribute__((ext_vector_type(4)));

#define DIM   1024
#define NT    128
#define BATCH 32768

// ---------------------------------------------------------------------------
// Prep: W[k][n] fp32 -> bf16 in B-fragment order.
// wsW[ ((s*8 + c)*64 + lane)*8 + j ] = W[ s*32 + (lane>>4)*8 + j ][ c*16 + (lane&15) ]
// ---------------------------------------------------------------------------
__global__ __launch_bounds__(256) void prep_w(const float* __restrict__ W,
                                              __bf16* __restrict__ wsW) {
    int idx = blockIdx.x * 256 + threadIdx.x;   // 0 .. 131071
    int j = idx & 7;
    int l = (idx >> 3) & 63;
    int c = (idx >> 9) & 7;
    int s = idx >> 12;
    int k = s * 32 + (l >> 4) * 8 + j;
    int n = c * 16 + (l & 15);
    wsW[idx] = (__bf16)W[k * NT + n];
}

// ---------------------------------------------------------------------------
// Main: block = 128 threads = 2 waves; wave handles 16 rows x 128 cols.
// Block covers 32 rows -> grid = 1024 blocks (4 blocks/CU, 2 waves/SIMD).
// A-frag (16x16x32): lane holds A[m = lane&15][k = (lane>>4)*8 + j]
// B-frag:            lane holds B[k = (lane>>4)*8 + j][n = lane&15]
// C/D:               col = lane&15, row = (lane>>4)*4 + reg
// ---------------------------------------------------------------------------
__global__ __launch_bounds__(128) void gemm_bias_sigmoid(
        const float* __restrict__ x,
        const __bf16* __restrict__ wsW,
        const float* __restrict__ bias,
        float* __restrict__ out) {
    const int lane = threadIdx.x & 63;
    const int wave = threadIdx.x >> 6;
    const int q    = lane >> 4;      // quad
    const int r    = lane & 15;
    const int row0 = blockIdx.x * 32 + wave * 16;

    // Per-lane A base: row (row0 + r), k offset q*8
    const float* xA = x + (size_t)(row0 + r) * DIM + q * 8;
    // B frags: wsW viewed as bf16x8[], index (s*8 + c)*64 + lane
    const bf16x8* wb = (const bf16x8*)wsW + lane;

    f32x4 acc[8];
#pragma unroll
    for (int c = 0; c < 8; ++c)
        acc[c] = (f32x4){0.f, 0.f, 0.f, 0.f};

    // Register double buffers (A raw fp32 + B frags)
    float4 abuf[2][2];
    bf16x8 bbuf[2][8];

    // Prologue: issue loads for step 0
    {
        abuf[0][0] = *(const float4*)(xA);
        abuf[0][1] = *(const float4*)(xA + 4);
#pragma unroll
        for (int c = 0; c < 8; ++c)
            bbuf[0][c] = wb[(size_t)c * 64];
    }

#pragma unroll 2
    for (int s = 0; s < 32; ++s) {
        const int cur = s & 1;
        const int nxt = cur ^ 1;

        // Issue next iteration's loads first (A = HBM, deepest latency)
        if (s < 31) {
            const float* ap = xA + (size_t)(s + 1) * 32;
            abuf[nxt][0] = *(const float4*)ap;
            abuf[nxt][1] = *(const float4*)(ap + 4);
            const bf16x8* wp = wb + (size_t)(s + 1) * 512;
#pragma unroll
            for (int c = 0; c < 8; ++c)
                bbuf[nxt][c] = wp[(size_t)c * 64];
        }

        // Convert current A to bf16 and run 8 MFMAs
        const float4 a0 = abuf[cur][0];
        const float4 a1 = abuf[cur][1];
        bf16x8 af;
        af[0] = (__bf16)a0.x; af[1] = (__bf16)a0.y;
        af[2] = (__bf16)a0.z; af[3] = (__bf16)a0.w;
        af[4] = (__bf16)a1.x; af[5] = (__bf16)a1.y;
        af[6] = (__bf16)a1.z; af[7] = (__bf16)a1.w;

#pragma unroll
        for (int c = 0; c < 8; ++c)
            acc[c] = __builtin_amdgcn_mfma_f32_16x16x32_bf16(
                af, bbuf[cur][c], acc[c], 0, 0, 0);
    }

    // ---- epilogue: bias + sigmoid + store ----
#pragma unroll
    for (int c = 0; c < 8; ++c) {
        const float bv = bias[c * 16 + r];
#pragma unroll
        for (int reg = 0; reg < 4; ++reg) {
            const int row = row0 + q * 4 + reg;
            float v = acc[c][reg] + bv;
            v = 1.0f / (1.0f + __expf(-v));
            out[(size_t)row * NT + c * 16 + r] = v;
        }
    }
}

extern "C" void kernel_launch(void* const* d_in, const int* in_sizes, int n_in,
                              void* d_out, int out_size, void* d_ws, size_t ws_size,
                              hipStream_t stream) {
    const float* x = (const float*)d_in[0];   // [32768,1024]
    const float* W = (const float*)d_in[1];   // [1024,128]
    const float* b = (const float*)d_in[2];   // [128]
    float* out     = (float*)d_out;           // [32768,128]
    __bf16* wsW    = (__bf16*)d_ws;           // 256 KB swizzled bf16 W

    prep_w<<<DIM * NT / 256, 256, 0, stream>>>(W, wsW);
    gemm_bias_sigmoid<<<BATCH / 32, 128, 0, stream>>>(x, wsW, b, out);
}

// Round 3
// 215.239 us; speedup vs baseline: 1.9691x; 1.9691x over previous
//
#include <hip/hip_runtime.h>
#include <hip/hip_bf16.h>

// Problem: out[32768,128] = sigmoid(x[32768,1024] @ W[1024,128] + b[128]), all fp32.
// Strategy: bf16 MFMA (16x16x32), W pre-converted+swizzled to B-fragment order in d_ws.
// R3: R2's dynamically-indexed double buffers spilled to scratch (VGPR 52, WRITE 531MB).
//     Rewritten as manual 2x-unrolled pipeline with NAMED buffer sets, constant indexing
//     only. Wave tile 16x128 (acc=32 VGPR), block=4 waves=64 rows, grid=512 (2 blk/CU).

typedef __bf16 bf16x8 __attribute__((ext_vector_type(8)));
typedef float  f32x4  __attribute__((ext_vector_type(4)));

#define DIM   1024
#define NT    128
#define BATCH 32768

// ---------------------------------------------------------------------------
// Prep: W[k][n] fp32 -> bf16 in B-fragment order.
// wsW[ ((s*8 + c)*64 + lane)*8 + j ] = W[ s*32 + (lane>>4)*8 + j ][ c*16 + (lane&15) ]
// ---------------------------------------------------------------------------
__global__ __launch_bounds__(256) void prep_w(const float* __restrict__ W,
                                              __bf16* __restrict__ wsW) {
    int idx = blockIdx.x * 256 + threadIdx.x;   // 0 .. 131071
    int j = idx & 7;
    int l = (idx >> 3) & 63;
    int c = (idx >> 9) & 7;
    int s = idx >> 12;
    int k = s * 32 + (l >> 4) * 8 + j;
    int n = c * 16 + (l & 15);
    wsW[idx] = (__bf16)W[k * NT + n];
}

__device__ __forceinline__ bf16x8 cvt_bf16x8(float4 a0, float4 a1) {
    bf16x8 af;
    af[0] = (__bf16)a0.x; af[1] = (__bf16)a0.y;
    af[2] = (__bf16)a0.z; af[3] = (__bf16)a0.w;
    af[4] = (__bf16)a1.x; af[5] = (__bf16)a1.y;
    af[6] = (__bf16)a1.z; af[7] = (__bf16)a1.w;
    return af;
}

// ---------------------------------------------------------------------------
// Main: block = 256 threads = 4 waves; wave handles 16 rows x 128 cols.
// Block covers 64 rows -> grid = 512 blocks (2 blocks/CU, 8 waves/CU).
// A-frag (16x16x32): lane holds A[m = lane&15][k = (lane>>4)*8 + j]
// B-frag:            lane holds B[k = (lane>>4)*8 + j][n = lane&15]
// C/D:               col = lane&15, row = (lane>>4)*4 + reg
// ---------------------------------------------------------------------------
__global__ __launch_bounds__(256) void gemm_bias_sigmoid(
        const float* __restrict__ x,
        const __hip_bfloat16* __restrict__ wsWh,
        const float* __restrict__ bias,
        float* __restrict__ out) {
    const __bf16* wsW = (const __bf16*)wsWh;
    const int lane = threadIdx.x & 63;
    const int wave = threadIdx.x >> 6;
    const int q    = lane >> 4;      // quad
    const int r    = lane & 15;
    const int row0 = blockIdx.x * 64 + wave * 16;

    const float* xA = x + (size_t)(row0 + r) * DIM + q * 8;
    const bf16x8* wb = (const bf16x8*)wsW + lane;

    f32x4 acc[8];
#pragma unroll
    for (int c = 0; c < 8; ++c)
        acc[c] = (f32x4){0.f, 0.f, 0.f, 0.f};

    // ---- named double-buffer sets (no dynamic indexing anywhere) ----
    float4 aA0, aA1, aB0, aB1;
    bf16x8 bA[8], bB[8];     // only ever indexed by unrolled constants

    // prologue: s=0 -> A-set
    aA0 = *(const float4*)(xA);
    aA1 = *(const float4*)(xA + 4);
#pragma unroll
    for (int c = 0; c < 8; ++c)
        bA[c] = wb[(size_t)c * 64];

    for (int t = 0; t < 16; ++t) {
        const int s1 = 2 * t + 1;
        const int s2 = 2 * t + 2;

        // load s1 -> B-set (issued before any wait on A-set consumers)
        {
            const float* ap = xA + (size_t)s1 * 32;
            aB0 = *(const float4*)ap;
            aB1 = *(const float4*)(ap + 4);
            const bf16x8* wp = wb + (size_t)s1 * 512;
#pragma unroll
            for (int c = 0; c < 8; ++c)
                bB[c] = wp[(size_t)c * 64];
        }

        // compute s0 with A-set
        {
            const bf16x8 af = cvt_bf16x8(aA0, aA1);
#pragma unroll
            for (int c = 0; c < 8; ++c)
                acc[c] = __builtin_amdgcn_mfma_f32_16x16x32_bf16(af, bA[c], acc[c], 0, 0, 0);
        }

        // load s2 -> A-set
        if (t < 15) {
            const float* ap = xA + (size_t)s2 * 32;
            aA0 = *(const float4*)ap;
            aA1 = *(const float4*)(ap + 4);
            const bf16x8* wp = wb + (size_t)s2 * 512;
#pragma unroll
            for (int c = 0; c < 8; ++c)
                bA[c] = wp[(size_t)c * 64];
        }

        // compute s1 with B-set
        {
            const bf16x8 af = cvt_bf16x8(aB0, aB1);
#pragma unroll
            for (int c = 0; c < 8; ++c)
                acc[c] = __builtin_amdgcn_mfma_f32_16x16x32_bf16(af, bB[c], acc[c], 0, 0, 0);
        }
    }

    // ---- epilogue: bias + sigmoid + store ----
#pragma unroll
    for (int c = 0; c < 8; ++c) {
        const float bv = bias[c * 16 + r];
#pragma unroll
        for (int reg = 0; reg < 4; ++reg) {
            const int row = row0 + q * 4 + reg;
            float v = acc[c][reg] + bv;
            v = 1.0f / (1.0f + __expf(-v));
            out[(size_t)row * NT + c * 16 + r] = v;
        }
    }
}

extern "C" void kernel_launch(void* const* d_in, const int* in_sizes, int n_in,
                              void* d_out, int out_size, void* d_ws, size_t ws_size,
                              hipStream_t stream) {
    const float* x = (const float*)d_in[0];   // [32768,1024]
    const float* W = (const float*)d_in[1];   // [1024,128]
    const float* b = (const float*)d_in[2];   // [128]
    float* out     = (float*)d_out;           // [32768,128]
    __bf16* wsW    = (__bf16*)d_ws;           // 256 KB swizzled bf16 W

    prep_w<<<DIM * NT / 256, 256, 0, stream>>>(W, wsW);
    gemm_bias_sigmoid<<<BATCH / 64, 256, 0, stream>>>(
        x, (const __hip_bfloat16*)wsW, b, out);
}

// Round 4
// 203.454 us; speedup vs baseline: 2.0831x; 1.0579x over previous
//
#include <hip/hip_runtime.h>
#include <hip/hip_bf16.h>

// Problem: out[32768,128] = sigmoid(x[32768,1024] @ W[1024,128] + b[128]), all fp32.
// R4: decouple streams. W staged to LDS in 4 phases (64KB each) -> B-frag reads are
//     ds_read_b128 (lgkmcnt), vm queue is PURE A-stream (HBM). A loaded in 4-step
//     named half-phase bursts (constant-indexed, spill-proof). Block = 4 waves
//     (64 rows), grid = 512 -> 2 blocks/CU, phase-desynced for HBM overlap.

typedef __bf16 bf16x8 __attribute__((ext_vector_type(8)));
typedef float  f32x4  __attribute__((ext_vector_type(4)));

#define DIM   1024
#define NT    128
#define BATCH 32768

// ---------------------------------------------------------------------------
// Prep: W[k][n] fp32 -> bf16 in B-fragment order.
// wsW[ ((s*8 + c)*64 + lane)*8 + j ] = W[ s*32 + (lane>>4)*8 + j ][ c*16 + (lane&15) ]
// ---------------------------------------------------------------------------
__global__ __launch_bounds__(256) void prep_w(const float* __restrict__ W,
                                              __bf16* __restrict__ wsW) {
    int idx = blockIdx.x * 256 + threadIdx.x;   // 0 .. 131071
    int j = idx & 7;
    int l = (idx >> 3) & 63;
    int c = (idx >> 9) & 7;
    int s = idx >> 12;
    int k = s * 32 + (l >> 4) * 8 + j;
    int n = c * 16 + (l & 15);
    wsW[idx] = (__bf16)W[k * NT + n];
}

__device__ __forceinline__ bf16x8 cvt_bf16x8(float4 a0, float4 a1) {
    bf16x8 af;
    af[0] = (__bf16)a0.x; af[1] = (__bf16)a0.y;
    af[2] = (__bf16)a0.z; af[3] = (__bf16)a0.w;
    af[4] = (__bf16)a1.x; af[5] = (__bf16)a1.y;
    af[6] = (__bf16)a1.z; af[7] = (__bf16)a1.w;
    return af;
}

// ---------------------------------------------------------------------------
// Main: block = 256 threads = 4 waves; wave tile 16 rows x 128 cols (acc = 32 VGPR).
// Block = 64 rows -> grid = 512 (2 blocks/CU; LDS 64KB each).
// 4 phases of 8 k-steps; per phase: stage 64KB W-chunk to LDS + burst-load A.
// A-frag (16x16x32): lane holds A[m = lane&15][k = (lane>>4)*8 + j]
// B-frag:            lane holds B[k = (lane>>4)*8 + j][n = lane&15]
// C/D:               col = lane&15, row = (lane>>4)*4 + reg
// ---------------------------------------------------------------------------
__global__ __launch_bounds__(256) void gemm_bias_sigmoid(
        const float* __restrict__ x,
        const __hip_bfloat16* __restrict__ wsWh,
        const float* __restrict__ bias,
        float* __restrict__ out) {
    const bf16x8* __restrict__ wsW8 = (const bf16x8*)wsWh;  // frag units of 16B
    __shared__ bf16x8 ldsW[4096];                           // 64 KB: 64 frags x 64 lanes

    const int tid  = threadIdx.x;
    const int lane = tid & 63;
    const int wave = tid >> 6;
    const int q    = lane >> 4;
    const int r    = lane & 15;
    const int row0 = blockIdx.x * 64 + wave * 16;

    const float* xA = x + (size_t)(row0 + r) * DIM + q * 8;

    f32x4 acc[8];
#pragma unroll
    for (int c = 0; c < 8; ++c)
        acc[c] = (f32x4){0.f, 0.f, 0.f, 0.f};

    // Named half-phase A buffers (4 k-steps each); constant indexing only.
    float4 S0[8], S1[8];

    // Prologue: A for steps 0..3
#pragma unroll
    for (int i = 0; i < 4; ++i) {
        const float* ap = xA + (size_t)i * 32;
        S0[2 * i]     = *(const float4*)ap;
        S0[2 * i + 1] = *(const float4*)(ap + 4);
    }

    for (int p = 0; p < 4; ++p) {
        __syncthreads();   // previous phase's LDS reads complete
        // ---- stage W phase p: 64 KB, linear, coalesced 16B/thread x16 ----
#pragma unroll
        for (int i = 0; i < 16; ++i) {
            const int e = tid + i * 256;
            ldsW[e] = wsW8[p * 4096 + e];
        }
        // ---- A for steps p*8+4 .. p*8+7 ----
#pragma unroll
        for (int i = 0; i < 4; ++i) {
            const float* ap = xA + (size_t)(p * 8 + 4 + i) * 32;
            S1[2 * i]     = *(const float4*)ap;
            S1[2 * i + 1] = *(const float4*)(ap + 4);
        }
        __syncthreads();   // staging visible

        // ---- compute steps p*8 .. p*8+3 from S0 ----
#pragma unroll
        for (int sl = 0; sl < 4; ++sl) {
            const bf16x8 af = cvt_bf16x8(S0[2 * sl], S0[2 * sl + 1]);
#pragma unroll
            for (int c = 0; c < 8; ++c) {
                const bf16x8 bf = ldsW[(sl * 8 + c) * 64 + lane];
                acc[c] = __builtin_amdgcn_mfma_f32_16x16x32_bf16(af, bf, acc[c], 0, 0, 0);
            }
        }
        // ---- prefetch next phase first half into S0 ----
        if (p < 3) {
#pragma unroll
            for (int i = 0; i < 4; ++i) {
                const float* ap = xA + (size_t)((p + 1) * 8 + i) * 32;
                S0[2 * i]     = *(const float4*)ap;
                S0[2 * i + 1] = *(const float4*)(ap + 4);
            }
        }
        // ---- compute steps p*8+4 .. p*8+7 from S1 ----
#pragma unroll
        for (int sl = 4; sl < 8; ++sl) {
            const bf16x8 af = cvt_bf16x8(S1[2 * (sl - 4)], S1[2 * (sl - 4) + 1]);
#pragma unroll
            for (int c = 0; c < 8; ++c) {
                const bf16x8 bf = ldsW[(sl * 8 + c) * 64 + lane];
                acc[c] = __builtin_amdgcn_mfma_f32_16x16x32_bf16(af, bf, acc[c], 0, 0, 0);
            }
        }
    }

    // ---- epilogue: bias + sigmoid + store ----
#pragma unroll
    for (int c = 0; c < 8; ++c) {
        const float bv = bias[c * 16 + r];
#pragma unroll
        for (int reg = 0; reg < 4; ++reg) {
            const int row = row0 + q * 4 + reg;
            float v = acc[c][reg] + bv;
            v = 1.0f / (1.0f + __expf(-v));
            out[(size_t)row * NT + c * 16 + r] = v;
        }
    }
}

extern "C" void kernel_launch(void* const* d_in, const int* in_sizes, int n_in,
                              void* d_out, int out_size, void* d_ws, size_t ws_size,
                              hipStream_t stream) {
    const float* x = (const float*)d_in[0];   // [32768,1024]
    const float* W = (const float*)d_in[1];   // [1024,128]
    const float* b = (const float*)d_in[2];   // [128]
    float* out     = (float*)d_out;           // [32768,128]
    __bf16* wsW    = (__bf16*)d_ws;           // 256 KB swizzled bf16 W

    prep_w<<<DIM * NT / 256, 256, 0, stream>>>(W, wsW);
    gemm_bias_sigmoid<<<BATCH / 64, 256, 0, stream>>>(
        x, (const __hip_bfloat16*)wsW, b, out);
}